// Round 10
// baseline (475.730 us; speedup 1.0000x reference)
//
#include <hip/hip_runtime.h>

// =====================================================================
// GraphAutoEncoder forward. GCN via CSR build + gather.
// R18: split paid once (W pre-split planes; A split during staging).
// R19 post-mortem-driven: (a) gcn_agg was outstanding-bytes-limited
// (4 gathers x 256B = 1KB/wave -> 3.4TB/s); unroll 8 -> 2KB/wave.
// (b) small-K GEMMs re-paid A-stage latency per feat-tile block; now
// feat-tiles folded INTO the block (acc[FT][2][2], A staged once per
// k-step for all FT, B loads 16x16B in flight). 782 blocks all layers.
// =====================================================================

constexpr int NBLK = 128;           // scatter blocks (chunk = E/128)
constexpr int GRP  = NBLK / 8;      // block-groups per XCD residue

typedef __attribute__((ext_vector_type(8))) short bf16x8;
typedef __attribute__((ext_vector_type(4))) float f32x4;

__device__ inline void split2(float f0, float f1, unsigned& hp, unsigned& lp) {
    unsigned u0 = __float_as_uint(f0), u1 = __float_as_uint(f1);
    hp = (u1 & 0xFFFF0000u) | (u0 >> 16);
    float r0 = f0 - __uint_as_float(u0 & 0xFFFF0000u);
    float r1 = f1 - __uint_as_float(u1 & 0xFFFF0000u);
    lp = (__float_as_uint(r1) & 0xFFFF0000u) | (__float_as_uint(r0) >> 16);
}

struct Bf16Pair { bf16x8 h, l; };
__device__ inline Bf16Pair split8(float4 a, float4 b) {
    union { unsigned u[4]; bf16x8 v; } H, L;
    split2(a.x, a.y, H.u[0], L.u[0]);
    split2(a.z, a.w, H.u[1], L.u[1]);
    split2(b.x, b.y, H.u[2], L.u[2]);
    split2(b.z, b.w, H.u[3], L.u[3]);
    Bf16Pair p; p.h = H.v; p.l = L.v; return p;
}

// ---------------- weight pre-split: fp32 -> bf16 hi/lo planes --------
struct WSplitArgs {
    const float* src[6];
    unsigned short* hi[6];
    unsigned short* lo[6];
    int n[6];
};
__global__ __launch_bounds__(256) void split_w(WSplitArgs a) {
    const int L = blockIdx.y;
    const int i = blockIdx.x * 256 + threadIdx.x;
    if (i < a.n[L]) {
        float f = a.src[L][i];
        unsigned u = __float_as_uint(f);
        float r = f - __uint_as_float(u & 0xFFFF0000u);
        a.hi[L][i] = (unsigned short)(u >> 16);
        a.lo[L][i] = (unsigned short)(__float_as_uint(r) >> 16);
    }
}

// ---------------- GEMM: C = act(A @ W^T + b), all feat tiles in-block
// fp32 A in/C out. W pre-split planes. BM=64 nodes, FT tiles of 64
// feats, KS=64. 256 thr = 4 waves (2Mx2N, wave tile 32x32).
// grid = ceil(N/64) = 782 blocks for every layer.
template <int K, int M, int FT, int ACT, bool BIAS>
__global__ __launch_bounds__(256) void gemm_ft(const float* __restrict__ A,
                                               const unsigned short* __restrict__ Whp,
                                               const unsigned short* __restrict__ Wlp,
                                               const float* __restrict__ bias,
                                               float* __restrict__ C, int N) {
    static_assert(K % 64 == 0, "K%64");
    static_assert(FT * 64 == M, "FT*64==M");
    constexpr int KS = 64;
    // stride 72 ushorts = 144B == 16 (mod 128): conflict-free r/w
    __shared__ __align__(16) unsigned short Ah[64][72];
    __shared__ __align__(16) unsigned short Al[64][72];

    const int tid      = threadIdx.x;
    const int lane     = tid & 63;
    const int wid      = tid >> 6;
    const int wm       = wid >> 1;
    const int wn       = wid & 1;
    const int fr       = lane & 15;
    const int fg       = lane >> 4;
    const int nodeBase = blockIdx.x * 64;

    // staging coords: 4 threads per row, 16 floats each
    const int srow = tid >> 2;
    const int sc0  = (tid & 3) * 16;
    int grow = nodeBase + srow;
    if (grow >= N) grow = N - 1;
    const float* aptr = A + (size_t)grow * K + sc0;

    float4 av[4];
#pragma unroll
    for (int i = 0; i < 4; ++i) av[i] = *(const float4*)(aptr + i * 4);

    f32x4 acc[FT][2][2];
#pragma unroll
    for (int ft = 0; ft < FT; ++ft)
#pragma unroll
        for (int mf = 0; mf < 2; ++mf)
#pragma unroll
            for (int nf = 0; nf < 2; ++nf) acc[ft][mf][nf] = (f32x4)0.f;

    for (int kc = 0; kc < K; kc += KS) {
        // split once, commit bf16 planes to LDS
        {
            Bf16Pair p0 = split8(av[0], av[1]);
            Bf16Pair p1 = split8(av[2], av[3]);
            *(bf16x8*)&Ah[srow][sc0]     = p0.h;
            *(bf16x8*)&Ah[srow][sc0 + 8] = p1.h;
            *(bf16x8*)&Al[srow][sc0]     = p0.l;
            *(bf16x8*)&Al[srow][sc0 + 8] = p1.l;
        }
        __syncthreads();

        // prefetch next A tile into regs (drains during compute)
        if (kc + KS < K) {
#pragma unroll
            for (int i = 0; i < 4; ++i)
                av[i] = *(const float4*)(aptr + kc + KS + i * 4);
        }

#pragma unroll
        for (int kf = 0; kf < 2; ++kf) {
            const int kcol = kf * 32 + fg * 8;
            bf16x8 ah[2], al[2];
#pragma unroll
            for (int mf = 0; mf < 2; ++mf) {
                const int r = wm * 32 + mf * 16 + fr;
                ah[mf] = *(const bf16x8*)&Ah[r][kcol];
                al[mf] = *(const bf16x8*)&Al[r][kcol];
            }
#pragma unroll
            for (int ft = 0; ft < FT; ++ft) {
                bf16x8 bh[2], bl[2];
#pragma unroll
                for (int nf = 0; nf < 2; ++nf) {
                    const size_t wo =
                        (size_t)(ft * 64 + wn * 32 + nf * 16 + fr) * K + kc + kcol;
                    bh[nf] = *(const bf16x8*)(Whp + wo);
                    bl[nf] = *(const bf16x8*)(Wlp + wo);
                }
#pragma unroll
                for (int mf = 0; mf < 2; ++mf)
#pragma unroll
                    for (int nf = 0; nf < 2; ++nf) {
                        acc[ft][mf][nf] = __builtin_amdgcn_mfma_f32_16x16x32_bf16(
                            ah[mf], bh[nf], acc[ft][mf][nf], 0, 0, 0);
                        acc[ft][mf][nf] = __builtin_amdgcn_mfma_f32_16x16x32_bf16(
                            al[mf], bh[nf], acc[ft][mf][nf], 0, 0, 0);
                        acc[ft][mf][nf] = __builtin_amdgcn_mfma_f32_16x16x32_bf16(
                            ah[mf], bl[nf], acc[ft][mf][nf], 0, 0, 0);
                    }
            }
        }
        __syncthreads();
    }

    // epilogue: D[row=(lane>>4)*4+i][col=lane&15] per frag (R14-18 verified)
#pragma unroll
    for (int ft = 0; ft < FT; ++ft)
#pragma unroll
    for (int nf = 0; nf < 2; ++nf) {
        const int feat = ft * 64 + wn * 32 + nf * 16 + fr;
        const float bv = BIAS ? bias[feat] : 0.f;
#pragma unroll
        for (int mf = 0; mf < 2; ++mf) {
            const int node0 = nodeBase + wm * 32 + mf * 16 + fg * 4;
#pragma unroll
            for (int i = 0; i < 4; ++i) {
                const int node = node0 + i;
                if (node < N) {
                    float x = acc[ft][mf][nf][i] + bv;
                    if constexpr (ACT == 1) x = fmaxf(x, 0.f);
                    if constexpr (ACT == 2) x = 1.f / (1.f + __expf(-x));
                    C[(size_t)node * M + feat] = x;
                }
            }
        }
    }
}

// ---------------- CSR build: deterministic counting sort -------------

__global__ __launch_bounds__(256) void count_k(const int* __restrict__ ei,
                                               int* __restrict__ cnt,
                                               int NB, int E) {
    __shared__ int hist[784];
    const int tid = threadIdx.x;
    for (int i = tid; i < NB; i += 256) hist[i] = 0;
    __syncthreads();
    const int chunk = (E + NBLK - 1) / NBLK;
    const int lo = blockIdx.x * chunk;
    const int hi = min(lo + chunk, E);
    for (int e = lo + tid; e < hi; e += 256) {
        int d = ei[E + e];
        atomicAdd(&hist[d >> 6], 1);
    }
    __syncthreads();
    const int r = blockIdx.x & 7, g = blockIdx.x >> 3;
    for (int i = tid; i < NB; i += 256)
        cnt[i * NBLK + r * GRP + g] = hist[i];
}

__global__ __launch_bounds__(256) void scan1(const int* __restrict__ cnt,
                                             int* __restrict__ pos,
                                             int* __restrict__ bs, int n) {
    __shared__ int s[256];
    const int t = threadIdx.x;
    const int i0 = blockIdx.x * 512 + 2 * t;
    int c0 = (i0     < n) ? cnt[i0]     : 0;
    int c1 = (i0 + 1 < n) ? cnt[i0 + 1] : 0;
    int c = c0 + c1;
    s[t] = c;
    __syncthreads();
    for (int off = 1; off < 256; off <<= 1) {
        int v = (t >= off) ? s[t - off] : 0;
        __syncthreads();
        s[t] += v;
        __syncthreads();
    }
    int excl = s[t] - c;
    if (i0     < n) pos[i0]     = excl;
    if (i0 + 1 < n) pos[i0 + 1] = excl + c0;
    if (t == 255) bs[blockIdx.x] = s[255];
}

__global__ __launch_bounds__(256) void scan_tops(int* __restrict__ bs, int nb) {
    __shared__ int s[256];
    int t = threadIdx.x;
    int v = (t < nb) ? bs[t] : 0;
    s[t] = v;
    __syncthreads();
    for (int off = 1; off < 256; off <<= 1) {
        int u = (t >= off) ? s[t - off] : 0;
        __syncthreads();
        s[t] += u;
        __syncthreads();
    }
    if (t < nb) bs[t] = s[t] - v;
}

__global__ __launch_bounds__(256) void scan2(int* __restrict__ pos,
                                             const int* __restrict__ bs,
                                             int* __restrict__ bucketBase,
                                             int n, int NB, int E) {
    const int t = threadIdx.x;
    const int i0 = blockIdx.x * 512 + 2 * t;
    const int add = bs[blockIdx.x];
#pragma unroll
    for (int c = 0; c < 2; ++c) {
        int i = i0 + c;
        if (i < n) {
            int v = pos[i] + add;
            pos[i] = v;
            if ((i & (NBLK - 1)) == 0) bucketBase[i >> 7] = v;
        }
    }
    if (blockIdx.x == 0 && t == 0) bucketBase[NB] = E;
}

__global__ __launch_bounds__(256) void place_k(const int* __restrict__ ei,
                                               const float* __restrict__ w,
                                               const int* __restrict__ pos,
                                               int2* __restrict__ ebuf,
                                               int NB, int E) {
    __shared__ int cur[784];
    const int tid = threadIdx.x;
    const int r = blockIdx.x & 7, g = blockIdx.x >> 3;
    for (int i = tid; i < NB; i += 256) cur[i] = pos[i * NBLK + r * GRP + g];
    __syncthreads();
    const int chunk = (E + NBLK - 1) / NBLK;
    const int lo = blockIdx.x * chunk;
    const int hi = min(lo + chunk, E);
    for (int e = lo + tid; e < hi; e += 256) {
        int s = ei[e];
        int d = ei[E + e];
        float wv = w[e];
        int p = atomicAdd(&cur[d >> 6], 1);  // LDS atomic
        ebuf[p] = make_int2(s | ((d & 63) << 26), __float_as_int(wv));
    }
}

__global__ __launch_bounds__(256) void bucket_build(const int2* __restrict__ ebuf,
                                                    const int* __restrict__ bucketBase,
                                                    int2* __restrict__ sn,
                                                    int* __restrict__ row,
                                                    float* __restrict__ dinv,
                                                    int N, int E) {
    __shared__ int   lh[64];
    __shared__ float ldg[64];
    __shared__ int   sc[64];
    __shared__ int   lofs[64];
    const int tid  = threadIdx.x;
    const int base = bucketBase[blockIdx.x];
    const int end  = bucketBase[blockIdx.x + 1];

    if (tid < 64) { lh[tid] = 0; ldg[tid] = 0.f; }
    __syncthreads();
    for (int i = base + tid; i < end; i += 256) {
        int2 v = ebuf[i];
        int dl = ((unsigned)v.x) >> 26;
        atomicAdd(&lh[dl], 1);
        atomicAdd(&ldg[dl], __int_as_float(v.y));
    }
    __syncthreads();
    if (tid < 64) sc[tid] = lh[tid];
    __syncthreads();
    for (int off = 1; off < 64; off <<= 1) {
        int v = (tid < 64 && tid >= off) ? sc[tid - off] : 0;
        __syncthreads();
        if (tid < 64) sc[tid] += v;
        __syncthreads();
    }
    if (tid < 64) {
        int excl = sc[tid] - lh[tid];
        int d = (blockIdx.x << 6) + tid;
        if (d < N) {
            row[d]  = base + excl;
            dinv[d] = rsqrtf(fmaxf(1.0f + ldg[tid], 1e-12f));  // + self-loop
        }
        lofs[tid] = base + excl;
    }
    __syncthreads();
    for (int i = base + tid; i < end; i += 256) {
        int2 v = ebuf[i];
        unsigned u = (unsigned)v.x;
        int dl = u >> 26;
        int s  = u & 0x03FFFFFF;
        int p  = atomicAdd(&lofs[dl], 1);
        sn[p] = make_int2(s, v.y);
    }
    if (blockIdx.x == 0 && tid == 0) row[N] = E;
}

// payload.y <- w * dinv[src]
__global__ __launch_bounds__(256) void scale_pay(int2* __restrict__ sn,
                                                 const float* __restrict__ dinv,
                                                 int E) {
    int p = blockIdx.x * 256 + threadIdx.x;
    if (p < E) {
        int2 v = sn[p];
        sn[p] = make_int2(v.x, __float_as_int(__int_as_float(v.y) * dinv[v.x]));
    }
}

// ---------------- fused GCN aggregation (gather, no atomics) ---------
// 8-deep gather unroll: 8 x 256B in flight per wave (R18 had 4 -> 1KB,
// measured 3.4TB/s = outstanding-bytes-limited).
__global__ __launch_bounds__(256) void gcn_agg(const float* __restrict__ t,
                                               const int2* __restrict__ sn,
                                               const int* __restrict__ row,
                                               const float* __restrict__ dinv,
                                               const float* __restrict__ bias,
                                               float* __restrict__ out, int N) {
    const int lane = threadIdx.x & 63;
    int i = __builtin_amdgcn_readfirstlane((int)(blockIdx.x * 4) + (threadIdx.x >> 6));
    if (i >= N) return;
    float di   = dinv[i];
    float self = t[(size_t)i * 64 + lane];
    float acc  = 0.f;
    int p  = row[i];
    int pe = row[i + 1];
    for (; p + 8 <= pe; p += 8) {
        int2 v[8];
#pragma unroll
        for (int j = 0; j < 8; ++j) v[j] = sn[p + j];
        float partial = 0.f;
#pragma unroll
        for (int j = 0; j < 8; ++j)
            partial += t[(size_t)v[j].x * 64 + lane] * __int_as_float(v[j].y);
        acc += partial;
    }
    for (; p < pe; ++p) {
        int2 v = sn[p];
        acc += t[(size_t)v.x * 64 + lane] * __int_as_float(v.y);
    }
    float x = (acc + self * di) * di + bias[lane];
    out[(size_t)i * 64 + lane] = fmaxf(x, 0.f);
}

// =====================================================================
extern "C" void kernel_launch(void* const* d_in, const int* in_sizes, int n_in,
                              void* d_out, int out_size, void* d_ws, size_t ws_size,
                              hipStream_t stream) {
    const float* x      = (const float*)d_in[0];
    const int*   ei     = (const int*)d_in[1];   // int32 per harness contract
    const float* ew     = (const float*)d_in[2];
    const float* enc1_w = (const float*)d_in[3];
    const float* enc1_b = (const float*)d_in[4];
    const float* enc2_w = (const float*)d_in[5];
    const float* enc2_b = (const float*)d_in[6];
    const float* gcn1_w = (const float*)d_in[7];
    const float* gcn1_b = (const float*)d_in[8];
    const float* gcn2_w = (const float*)d_in[9];
    const float* gcn2_b = (const float*)d_in[10];
    const float* dec1_w = (const float*)d_in[11];
    const float* dec1_b = (const float*)d_in[12];
    const float* dec2_w = (const float*)d_in[13];
    const float* dec2_b = (const float*)d_in[14];

    const int N  = in_sizes[0] / 256;    // 50000
    const int E  = in_sizes[2];          // 1600000
    const int NB = (N + 63) / 64;        // 782 buckets
    const int NCNT = NB * NBLK;          // 100096 counters
    const int NS   = (NCNT + 511) / 512; // 196 scan blocks

    // workspace (~41 MB), lifetime-aliased (R4 layout + W planes):
    //  bufA [N*128 floats]: h1 -> { sn[E] int2 | ebuf[E] int2 (=bufC) } -> h5
    //  bufB [N*64]: h2/h3/h4 ; dinv[N]; row[N+1];
    //  cnt[NCNT]; pos[NCNT]; bucketBase[NB+1]; bs[256]; whi/wlo planes
    float* ws   = (float*)d_ws;
    float* bufA = ws;
    int2*  sn   = (int2*)bufA;                  // E int2 (first half of bufA)
    float* bufC = bufA + (size_t)2 * E;         // N*64 floats (second half)
    int2*  ebuf = (int2*)bufC;                  // aliases bufC during build
    float* bufB = bufA + (size_t)N * 128;       // N*64
    float* dinv = bufB + (size_t)N * 64;        // N
    int*   row  = (int*)(dinv + N);             // N+1
    int*   cnt  = row + (N + 1);                // NCNT
    int*   pos  = cnt + NCNT;                   // NCNT
    int*   bucketBase = pos + NCNT;             // NB+1
    int*   bs   = bucketBase + (NB + 1);        // 256
    unsigned short* whi = (unsigned short*)(bs + 256);  // 90112 ushorts
    unsigned short* wlo = whi + 90112;

    const int nodeTiles = (N + 63) / 64;        // 782
    const int nBlkE     = (E + 255) / 256;      // 6250

    // weight pre-split (runs once, ~720KB traffic)
    WSplitArgs wa;
    const float* wsrc[6] = {enc1_w, enc2_w, gcn1_w, gcn2_w, dec1_w, dec2_w};
    const int    wsz[6]  = {32768, 8192, 4096, 4096, 8192, 32768};
    const int    woff[6] = {0, 32768, 40960, 45056, 49152, 57344};
    for (int l = 0; l < 6; ++l) {
        wa.src[l] = wsrc[l];
        wa.hi[l]  = whi + woff[l];
        wa.lo[l]  = wlo + woff[l];
        wa.n[l]   = wsz[l];
    }
    split_w<<<dim3(128, 6), 256, 0, stream>>>(wa);

    // encoder
    gemm_ft<256, 128, 2, 1, true><<<nodeTiles, 256, 0, stream>>>(
        x, whi + woff[0], wlo + woff[0], enc1_b, bufA, N);
    gemm_ft<128, 64, 1, 1, true><<<nodeTiles, 256, 0, stream>>>(
        bufA, whi + woff[1], wlo + woff[1], enc2_b, bufB, N);

    // CSR build, zero global atomics (shared by both GCN layers)
    count_k<<<NBLK, 256, 0, stream>>>(ei, cnt, NB, E);
    scan1<<<NS, 256, 0, stream>>>(cnt, pos, bs, NCNT);
    scan_tops<<<1, 256, 0, stream>>>(bs, NS);
    scan2<<<NS, 256, 0, stream>>>(pos, bs, bucketBase, NCNT, NB, E);
    place_k<<<NBLK, 256, 0, stream>>>(ei, ew, pos, ebuf, NB, E);
    bucket_build<<<NB, 256, 0, stream>>>(ebuf, bucketBase, sn, row, dinv, N, E);
    scale_pay<<<nBlkE, 256, 0, stream>>>(sn, dinv, E);

    // GCN layer 1
    gemm_ft<64, 64, 1, 0, false><<<nodeTiles, 256, 0, stream>>>(
        bufB, whi + woff[2], wlo + woff[2], nullptr, bufC, N);
    gcn_agg<<<(N + 3) / 4, 256, 0, stream>>>(bufC, sn, row, dinv, gcn1_b, bufB, N);

    // GCN layer 2
    gemm_ft<64, 64, 1, 0, false><<<nodeTiles, 256, 0, stream>>>(
        bufB, whi + woff[3], wlo + woff[3], nullptr, bufC, N);
    gcn_agg<<<(N + 3) / 4, 256, 0, stream>>>(bufC, sn, row, dinv, gcn2_b, bufB, N);

    // decoder (bufA region free again: sn/ebuf dead after 2nd agg)
    gemm_ft<64, 128, 2, 1, true><<<nodeTiles, 256, 0, stream>>>(
        bufB, whi + woff[4], wlo + woff[4], dec1_b, bufA, N);
    gemm_ft<128, 256, 4, 2, true><<<nodeTiles, 256, 0, stream>>>(
        bufA, whi + woff[5], wlo + woff[5], dec2_b, (float*)d_out, N);
}

// Round 11
// 443.910 us; speedup vs baseline: 1.0717x; 1.0717x over previous
//
#include <hip/hip_runtime.h>

// =====================================================================
// GraphAutoEncoder forward. GCN via CSR build + gather.
// R19 post-mortem: FT-folding regressed dec2 (fewer, longer, serial
// blocks: Occ 45->14%). Reverted to R18 GEMM structure (separate
// feat-tile blocks, best measured). Kept R19's 8-deep agg unroll (its
// win). R20: five GEMM variants all pinned at ~55us with all counters
// idle -> blocks die after 1-2 k-steps, no steady state. Now GRID-
// STRIDE PERSISTENT: block loops 2 node-tiles (blocksPerFt=391 for
// enc1/dec1/dec2), prefetching next tile's A-chunk into regs during
// current tile's MFMA. W stays L1-warm across tiles. m204 XCD swizzle.
// =====================================================================

constexpr int NBLK = 128;           // scatter blocks (chunk = E/128)
constexpr int GRP  = NBLK / 8;      // block-groups per XCD residue

typedef __attribute__((ext_vector_type(8))) short bf16x8;
typedef __attribute__((ext_vector_type(4))) float f32x4;

__device__ inline void split2(float f0, float f1, unsigned& hp, unsigned& lp) {
    unsigned u0 = __float_as_uint(f0), u1 = __float_as_uint(f1);
    hp = (u1 & 0xFFFF0000u) | (u0 >> 16);
    float r0 = f0 - __uint_as_float(u0 & 0xFFFF0000u);
    float r1 = f1 - __uint_as_float(u1 & 0xFFFF0000u);
    lp = (__float_as_uint(r1) & 0xFFFF0000u) | (__float_as_uint(r0) >> 16);
}

struct Bf16Pair { bf16x8 h, l; };
__device__ inline Bf16Pair split8(float4 a, float4 b) {
    union { unsigned u[4]; bf16x8 v; } H, L;
    split2(a.x, a.y, H.u[0], L.u[0]);
    split2(a.z, a.w, H.u[1], L.u[1]);
    split2(b.x, b.y, H.u[2], L.u[2]);
    split2(b.z, b.w, H.u[3], L.u[3]);
    Bf16Pair p; p.h = H.v; p.l = L.v; return p;
}

// ---------------- weight pre-split: fp32 -> bf16 hi/lo planes --------
struct WSplitArgs {
    const float* src[6];
    unsigned short* hi[6];
    unsigned short* lo[6];
    int n[6];
};
__global__ __launch_bounds__(256) void split_w(WSplitArgs a) {
    const int L = blockIdx.y;
    const int i = blockIdx.x * 256 + threadIdx.x;
    if (i < a.n[L]) {
        float f = a.src[L][i];
        unsigned u = __float_as_uint(f);
        float r = f - __uint_as_float(u & 0xFFFF0000u);
        a.hi[L][i] = (unsigned short)(u >> 16);
        a.lo[L][i] = (unsigned short)(__float_as_uint(r) >> 16);
    }
}

// ---------------- persistent GEMM: C[:,ft*64:+64] = act(A @ W^T + b) -
// fp32 A in / C out; W pre-split planes. BM=64 nodes/tile, KS=64.
// 256 thr = 4 waves (2Mx2N, wave tile 32x32). grid = FTC*bpf blocks;
// block b -> ft = b%FTC fixed, tiles t = b/FTC, += bpf (persistent).
// Next A-chunk prefetched into regs during current MFMA phase.
template <int K, int M, int FTC, int ACT, bool BIAS>
__global__ __launch_bounds__(256) void gemm_ps(const float* __restrict__ A,
                                               const unsigned short* __restrict__ Whp,
                                               const unsigned short* __restrict__ Wlp,
                                               const float* __restrict__ bias,
                                               float* __restrict__ C, int N,
                                               int nodeTiles, int bpf) {
    static_assert(K % 64 == 0, "K%64");
    constexpr int KSTEPS = K / 64;
    // stride 72 ushorts = 144B (=9*16): 16B-aligned rows, conflict-free
    __shared__ __align__(16) unsigned short Ah[64][72];
    __shared__ __align__(16) unsigned short Al[64][72];

    // m204 bijective XCD swizzle on the flat block id
    const int nwg = gridDim.x;
    const int o   = blockIdx.x;
    const int xcd = o & 7, idx = o >> 3;
    const int q   = nwg >> 3, rr = nwg & 7;
    const int wgid = (xcd < rr ? xcd * (q + 1) : rr * (q + 1) + (xcd - rr) * q) + idx;
    const int ft   = wgid % FTC;
    const int foff = ft * 64;
    const int t0   = wgid / FTC;

    const int tid  = threadIdx.x;
    const int lane = tid & 63;
    const int wid  = tid >> 6;
    const int wm   = wid >> 1;
    const int wn   = wid & 1;
    const int fr   = lane & 15;
    const int fg   = lane >> 4;

    // staging coords: 4 threads per row, 16 floats each
    const int srow = tid >> 2;
    const int sc0  = (tid & 3) * 16;

    auto aPtr = [&](int tile) {
        int grow = tile * 64 + srow;
        if (grow >= N) grow = N - 1;
        return A + (size_t)grow * K + sc0;
    };

    float4 av[4], av2[4];
    if (t0 < nodeTiles) {
        const float* p = aPtr(t0);
#pragma unroll
        for (int i = 0; i < 4; ++i) av[i] = *(const float4*)(p + i * 4);
    }

    for (int t = t0; t < nodeTiles; t += bpf) {
        const float* apCur = aPtr(t);
        f32x4 acc[2][2];
#pragma unroll
        for (int mf = 0; mf < 2; ++mf)
#pragma unroll
            for (int nf = 0; nf < 2; ++nf) acc[mf][nf] = (f32x4)0.f;

#pragma unroll
        for (int ks = 0; ks < KSTEPS; ++ks) {
            const int kc = ks * 64;
            // split once, commit bf16 planes to LDS
            {
                Bf16Pair p0 = split8(av[0], av[1]);
                Bf16Pair p1 = split8(av[2], av[3]);
                *(bf16x8*)&Ah[srow][sc0]     = p0.h;
                *(bf16x8*)&Ah[srow][sc0 + 8] = p1.h;
                *(bf16x8*)&Al[srow][sc0]     = p0.l;
                *(bf16x8*)&Al[srow][sc0 + 8] = p1.l;
            }
            __syncthreads();

            // prefetch next chunk: (t, kc+64) or (t+bpf, 0) -- drains
            // during the MFMA phase below
            {
                const float* np = nullptr;
                if (ks + 1 < KSTEPS) {
                    np = apCur + kc + 64;
                } else if (t + bpf < nodeTiles) {
                    np = aPtr(t + bpf);
                }
                if (np) {
#pragma unroll
                    for (int i = 0; i < 4; ++i) av2[i] = *(const float4*)(np + i * 4);
                }
            }

#pragma unroll
            for (int kf = 0; kf < 2; ++kf) {
                const int kcol = kf * 32 + fg * 8;
                bf16x8 ah[2], al[2], bh[2], bl[2];
#pragma unroll
                for (int mf = 0; mf < 2; ++mf) {
                    const int r = wm * 32 + mf * 16 + fr;
                    ah[mf] = *(const bf16x8*)&Ah[r][kcol];
                    al[mf] = *(const bf16x8*)&Al[r][kcol];
                }
#pragma unroll
                for (int nf = 0; nf < 2; ++nf) {
                    const size_t wo = (size_t)(foff + wn * 32 + nf * 16 + fr) * K
                                      + kc + kcol;
                    bh[nf] = *(const bf16x8*)(Whp + wo);
                    bl[nf] = *(const bf16x8*)(Wlp + wo);
                }
#pragma unroll
                for (int mf = 0; mf < 2; ++mf)
#pragma unroll
                    for (int nf = 0; nf < 2; ++nf) {
                        acc[mf][nf] = __builtin_amdgcn_mfma_f32_16x16x32_bf16(
                            ah[mf], bh[nf], acc[mf][nf], 0, 0, 0);
                        acc[mf][nf] = __builtin_amdgcn_mfma_f32_16x16x32_bf16(
                            al[mf], bh[nf], acc[mf][nf], 0, 0, 0);
                        acc[mf][nf] = __builtin_amdgcn_mfma_f32_16x16x32_bf16(
                            ah[mf], bl[nf], acc[mf][nf], 0, 0, 0);
                    }
            }
            __syncthreads();
#pragma unroll
            for (int i = 0; i < 4; ++i) av[i] = av2[i];
        }

        // epilogue: D[row=(lane>>4)*4+i][col=lane&15] per frag
        const int nodeBase = t * 64;
#pragma unroll
        for (int nf = 0; nf < 2; ++nf) {
            const int feat = foff + wn * 32 + nf * 16 + fr;
            const float bv = BIAS ? bias[feat] : 0.f;
#pragma unroll
            for (int mf = 0; mf < 2; ++mf) {
                const int node0 = nodeBase + wm * 32 + mf * 16 + fg * 4;
#pragma unroll
                for (int i = 0; i < 4; ++i) {
                    const int node = node0 + i;
                    if (node < N) {
                        float x = acc[mf][nf][i] + bv;
                        if constexpr (ACT == 1) x = fmaxf(x, 0.f);
                        if constexpr (ACT == 2) x = 1.f / (1.f + __expf(-x));
                        C[(size_t)node * M + feat] = x;
                    }
                }
            }
        }
    }
}

// ---------------- CSR build: deterministic counting sort -------------

__global__ __launch_bounds__(256) void count_k(const int* __restrict__ ei,
                                               int* __restrict__ cnt,
                                               int NB, int E) {
    __shared__ int hist[784];
    const int tid = threadIdx.x;
    for (int i = tid; i < NB; i += 256) hist[i] = 0;
    __syncthreads();
    const int chunk = (E + NBLK - 1) / NBLK;
    const int lo = blockIdx.x * chunk;
    const int hi = min(lo + chunk, E);
    for (int e = lo + tid; e < hi; e += 256) {
        int d = ei[E + e];
        atomicAdd(&hist[d >> 6], 1);
    }
    __syncthreads();
    const int r = blockIdx.x & 7, g = blockIdx.x >> 3;
    for (int i = tid; i < NB; i += 256)
        cnt[i * NBLK + r * GRP + g] = hist[i];
}

__global__ __launch_bounds__(256) void scan1(const int* __restrict__ cnt,
                                             int* __restrict__ pos,
                                             int* __restrict__ bs, int n) {
    __shared__ int s[256];
    const int t = threadIdx.x;
    const int i0 = blockIdx.x * 512 + 2 * t;
    int c0 = (i0     < n) ? cnt[i0]     : 0;
    int c1 = (i0 + 1 < n) ? cnt[i0 + 1] : 0;
    int c = c0 + c1;
    s[t] = c;
    __syncthreads();
    for (int off = 1; off < 256; off <<= 1) {
        int v = (t >= off) ? s[t - off] : 0;
        __syncthreads();
        s[t] += v;
        __syncthreads();
    }
    int excl = s[t] - c;
    if (i0     < n) pos[i0]     = excl;
    if (i0 + 1 < n) pos[i0 + 1] = excl + c0;
    if (t == 255) bs[blockIdx.x] = s[255];
}

__global__ __launch_bounds__(256) void scan_tops(int* __restrict__ bs, int nb) {
    __shared__ int s[256];
    int t = threadIdx.x;
    int v = (t < nb) ? bs[t] : 0;
    s[t] = v;
    __syncthreads();
    for (int off = 1; off < 256; off <<= 1) {
        int u = (t >= off) ? s[t - off] : 0;
        __syncthreads();
        s[t] += u;
        __syncthreads();
    }
    if (t < nb) bs[t] = s[t] - v;
}

__global__ __launch_bounds__(256) void scan2(int* __restrict__ pos,
                                             const int* __restrict__ bs,
                                             int* __restrict__ bucketBase,
                                             int n, int NB, int E) {
    const int t = threadIdx.x;
    const int i0 = blockIdx.x * 512 + 2 * t;
    const int add = bs[blockIdx.x];
#pragma unroll
    for (int c = 0; c < 2; ++c) {
        int i = i0 + c;
        if (i < n) {
            int v = pos[i] + add;
            pos[i] = v;
            if ((i & (NBLK - 1)) == 0) bucketBase[i >> 7] = v;
        }
    }
    if (blockIdx.x == 0 && t == 0) bucketBase[NB] = E;
}

__global__ __launch_bounds__(256) void place_k(const int* __restrict__ ei,
                                               const float* __restrict__ w,
                                               const int* __restrict__ pos,
                                               int2* __restrict__ ebuf,
                                               int NB, int E) {
    __shared__ int cur[784];
    const int tid = threadIdx.x;
    const int r = blockIdx.x & 7, g = blockIdx.x >> 3;
    for (int i = tid; i < NB; i += 256) cur[i] = pos[i * NBLK + r * GRP + g];
    __syncthreads();
    const int chunk = (E + NBLK - 1) / NBLK;
    const int lo = blockIdx.x * chunk;
    const int hi = min(lo + chunk, E);
    for (int e = lo + tid; e < hi; e += 256) {
        int s = ei[e];
        int d = ei[E + e];
        float wv = w[e];
        int p = atomicAdd(&cur[d >> 6], 1);  // LDS atomic
        ebuf[p] = make_int2(s | ((d & 63) << 26), __float_as_int(wv));
    }
}

__global__ __launch_bounds__(256) void bucket_build(const int2* __restrict__ ebuf,
                                                    const int* __restrict__ bucketBase,
                                                    int2* __restrict__ sn,
                                                    int* __restrict__ row,
                                                    float* __restrict__ dinv,
                                                    int N, int E) {
    __shared__ int   lh[64];
    __shared__ float ldg[64];
    __shared__ int   sc[64];
    __shared__ int   lofs[64];
    const int tid  = threadIdx.x;
    const int base = bucketBase[blockIdx.x];
    const int end  = bucketBase[blockIdx.x + 1];

    if (tid < 64) { lh[tid] = 0; ldg[tid] = 0.f; }
    __syncthreads();
    for (int i = base + tid; i < end; i += 256) {
        int2 v = ebuf[i];
        int dl = ((unsigned)v.x) >> 26;
        atomicAdd(&lh[dl], 1);
        atomicAdd(&ldg[dl], __int_as_float(v.y));
    }
    __syncthreads();
    if (tid < 64) sc[tid] = lh[tid];
    __syncthreads();
    for (int off = 1; off < 64; off <<= 1) {
        int v = (tid < 64 && tid >= off) ? sc[tid - off] : 0;
        __syncthreads();
        if (tid < 64) sc[tid] += v;
        __syncthreads();
    }
    if (tid < 64) {
        int excl = sc[tid] - lh[tid];
        int d = (blockIdx.x << 6) + tid;
        if (d < N) {
            row[d]  = base + excl;
            dinv[d] = rsqrtf(fmaxf(1.0f + ldg[tid], 1e-12f));  // + self-loop
        }
        lofs[tid] = base + excl;
    }
    __syncthreads();
    for (int i = base + tid; i < end; i += 256) {
        int2 v = ebuf[i];
        unsigned u = (unsigned)v.x;
        int dl = u >> 26;
        int s  = u & 0x03FFFFFF;
        int p  = atomicAdd(&lofs[dl], 1);
        sn[p] = make_int2(s, v.y);
    }
    if (blockIdx.x == 0 && tid == 0) row[N] = E;
}

// payload.y <- w * dinv[src]
__global__ __launch_bounds__(256) void scale_pay(int2* __restrict__ sn,
                                                 const float* __restrict__ dinv,
                                                 int E) {
    int p = blockIdx.x * 256 + threadIdx.x;
    if (p < E) {
        int2 v = sn[p];
        sn[p] = make_int2(v.x, __float_as_int(__int_as_float(v.y) * dinv[v.x]));
    }
}

// ---------------- fused GCN aggregation (gather, no atomics) ---------
// 8-deep gather unroll: 2KB in flight per wave (R19 win, kept).
__global__ __launch_bounds__(256) void gcn_agg(const float* __restrict__ t,
                                               const int2* __restrict__ sn,
                                               const int* __restrict__ row,
                                               const float* __restrict__ dinv,
                                               const float* __restrict__ bias,
                                               float* __restrict__ out, int N) {
    const int lane = threadIdx.x & 63;
    int i = __builtin_amdgcn_readfirstlane((int)(blockIdx.x * 4) + (threadIdx.x >> 6));
    if (i >= N) return;
    float di   = dinv[i];
    float self = t[(size_t)i * 64 + lane];
    float acc  = 0.f;
    int p  = row[i];
    int pe = row[i + 1];
    for (; p + 8 <= pe; p += 8) {
        int2 v[8];
#pragma unroll
        for (int j = 0; j < 8; ++j) v[j] = sn[p + j];
        float partial = 0.f;
#pragma unroll
        for (int j = 0; j < 8; ++j)
            partial += t[(size_t)v[j].x * 64 + lane] * __int_as_float(v[j].y);
        acc += partial;
    }
    for (; p < pe; ++p) {
        int2 v = sn[p];
        acc += t[(size_t)v.x * 64 + lane] * __int_as_float(v.y);
    }
    float x = (acc + self * di) * di + bias[lane];
    out[(size_t)i * 64 + lane] = fmaxf(x, 0.f);
}

// =====================================================================
extern "C" void kernel_launch(void* const* d_in, const int* in_sizes, int n_in,
                              void* d_out, int out_size, void* d_ws, size_t ws_size,
                              hipStream_t stream) {
    const float* x      = (const float*)d_in[0];
    const int*   ei     = (const int*)d_in[1];   // int32 per harness contract
    const float* ew     = (const float*)d_in[2];
    const float* enc1_w = (const float*)d_in[3];
    const float* enc1_b = (const float*)d_in[4];
    const float* enc2_w = (const float*)d_in[5];
    const float* enc2_b = (const float*)d_in[6];
    const float* gcn1_w = (const float*)d_in[7];
    const float* gcn1_b = (const float*)d_in[8];
    const float* gcn2_w = (const float*)d_in[9];
    const float* gcn2_b = (const float*)d_in[10];
    const float* dec1_w = (const float*)d_in[11];
    const float* dec1_b = (const float*)d_in[12];
    const float* dec2_w = (const float*)d_in[13];
    const float* dec2_b = (const float*)d_in[14];

    const int N  = in_sizes[0] / 256;    // 50000
    const int E  = in_sizes[2];          // 1600000
    const int NB = (N + 63) / 64;        // 782 buckets
    const int NCNT = NB * NBLK;          // 100096 counters
    const int NS   = (NCNT + 511) / 512; // 196 scan blocks

    // workspace (~41 MB), lifetime-aliased (R4 layout + W planes):
    //  bufA [N*128 floats]: h1 -> { sn[E] int2 | ebuf[E] int2 (=bufC) } -> h5
    //  bufB [N*64]: h2/h3/h4 ; dinv[N]; row[N+1];
    //  cnt[NCNT]; pos[NCNT]; bucketBase[NB+1]; bs[256]; whi/wlo planes
    float* ws   = (float*)d_ws;
    float* bufA = ws;
    int2*  sn   = (int2*)bufA;                  // E int2 (first half of bufA)
    float* bufC = bufA + (size_t)2 * E;         // N*64 floats (second half)
    int2*  ebuf = (int2*)bufC;                  // aliases bufC during build
    float* bufB = bufA + (size_t)N * 128;       // N*64
    float* dinv = bufB + (size_t)N * 64;        // N
    int*   row  = (int*)(dinv + N);             // N+1
    int*   cnt  = row + (N + 1);                // NCNT
    int*   pos  = cnt + NCNT;                   // NCNT
    int*   bucketBase = pos + NCNT;             // NB+1
    int*   bs   = bucketBase + (NB + 1);        // 256
    unsigned short* whi = (unsigned short*)(bs + 256);  // 90112 ushorts
    unsigned short* wlo = whi + 90112;

    const int nodeTiles = (N + 63) / 64;        // 782
    const int halfTiles = (nodeTiles + 1) / 2;  // 391
    const int nBlkE     = (E + 255) / 256;      // 6250

    // weight pre-split (runs once, ~720KB traffic)
    WSplitArgs wa;
    const float* wsrc[6] = {enc1_w, enc2_w, gcn1_w, gcn2_w, dec1_w, dec2_w};
    const int    wsz[6]  = {32768, 8192, 4096, 4096, 8192, 32768};
    const int    woff[6] = {0, 32768, 40960, 45056, 49152, 57344};
    for (int l = 0; l < 6; ++l) {
        wa.src[l] = wsrc[l];
        wa.hi[l]  = whi + woff[l];
        wa.lo[l]  = wlo + woff[l];
        wa.n[l]   = wsz[l];
    }
    split_w<<<dim3(128, 6), 256, 0, stream>>>(wa);

    // encoder: enc1 persistent (2 tiles/block), enc2 1 tile/block
    gemm_ps<256, 128, 2, 1, true><<<2 * halfTiles, 256, 0, stream>>>(
        x, whi + woff[0], wlo + woff[0], enc1_b, bufA, N, nodeTiles, halfTiles);
    gemm_ps<128, 64, 1, 1, true><<<nodeTiles, 256, 0, stream>>>(
        bufA, whi + woff[1], wlo + woff[1], enc2_b, bufB, N, nodeTiles, nodeTiles);

    // CSR build, zero global atomics (shared by both GCN layers)
    count_k<<<NBLK, 256, 0, stream>>>(ei, cnt, NB, E);
    scan1<<<NS, 256, 0, stream>>>(cnt, pos, bs, NCNT);
    scan_tops<<<1, 256, 0, stream>>>(bs, NS);
    scan2<<<NS, 256, 0, stream>>>(pos, bs, bucketBase, NCNT, NB, E);
    place_k<<<NBLK, 256, 0, stream>>>(ei, ew, pos, ebuf, NB, E);
    bucket_build<<<NB, 256, 0, stream>>>(ebuf, bucketBase, sn, row, dinv, N, E);
    scale_pay<<<nBlkE, 256, 0, stream>>>(sn, dinv, E);

    // GCN layer 1
    gemm_ps<64, 64, 1, 0, false><<<nodeTiles, 256, 0, stream>>>(
        bufB, whi + woff[2], wlo + woff[2], nullptr, bufC, N, nodeTiles, nodeTiles);
    gcn_agg<<<(N + 3) / 4, 256, 0, stream>>>(bufC, sn, row, dinv, gcn1_b, bufB, N);

    // GCN layer 2
    gemm_ps<64, 64, 1, 0, false><<<nodeTiles, 256, 0, stream>>>(
        bufB, whi + woff[3], wlo + woff[3], nullptr, bufC, N, nodeTiles, nodeTiles);
    gcn_agg<<<(N + 3) / 4, 256, 0, stream>>>(bufC, sn, row, dinv, gcn2_b, bufB, N);

    // decoder: dec1/dec2 persistent (2 tiles/block)
    gemm_ps<64, 128, 2, 1, true><<<2 * halfTiles, 256, 0, stream>>>(
        bufB, whi + woff[4], wlo + woff[4], dec1_b, bufA, N, nodeTiles, halfTiles);
    gemm_ps<128, 256, 4, 2, true><<<4 * halfTiles, 256, 0, stream>>>(
        bufA, whi + woff[5], wlo + woff[5], dec2_b, (float*)d_out, N, nodeTiles, halfTiles);
}